// Round 1
// baseline (11602.557 us; speedup 1.0000x reference)
//
#include <hip/hip_runtime.h>
#include <hip/hip_cooperative_groups.h>
#include <cstdint>
#include <cstddef>

namespace cg = cooperative_groups;

// Problem constants
#define BATCH 512
#define HDIM  1024
#define SENC  128
#define SDEC  31
#define NSTEPS 159          // 128 encoder + 31 decoder
#define KTOT  1152          // 128 (x) + 1024 (h)
#define NKI   36            // K-iterations of 32
#define HB    524288        // elements per h buffer (512*1024)
#define SLAB_ELEMS 55296    // per-c weight slab: 36*3*64*8 shorts
#define FRAG_TOTAL 442368   // 64*36*3*64 fragment slots

typedef short  short8  __attribute__((ext_vector_type(8)));
typedef float  floatx4 __attribute__((ext_vector_type(4)));
typedef float  f32x4   __attribute__((ext_vector_type(4)));

#define MFMA(a, b, c) __builtin_amdgcn_mfma_f32_16x16x32_bf16((a), (b), (c), 0, 0, 0)

// ---------- bf16 helpers (RNE) ----------
__device__ __forceinline__ float bf2f(short s) {
    return __uint_as_float(((unsigned)(unsigned short)s) << 16);
}
__device__ __forceinline__ short f2bf(float f) {
    unsigned u = __float_as_uint(f);
    return (short)((u + 0x7FFFu + ((u >> 16) & 1u)) >> 16);
}
__device__ __forceinline__ void f2pair(float f, short& hi, short& lo) {
    hi = f2bf(f);
    lo = f2bf(f - bf2f(hi));
}
// load 8 fp32 (32B, 16B-aligned) -> hi/lo bf16 fragments
__device__ __forceinline__ void cvt8(const float* __restrict__ src, short8& hi, short8& lo) {
    f32x4 a = ((const f32x4*)src)[0];
    f32x4 b = ((const f32x4*)src)[1];
    float f[8];
#pragma unroll
    for (int j = 0; j < 4; ++j) { f[j] = a[j]; f[4 + j] = b[j]; }
#pragma unroll
    for (int j = 0; j < 8; ++j) {
        short h, l;
        f2pair(f[j], h, l);
        hi[j] = h; lo[j] = l;
    }
}

__device__ __forceinline__ float sigm(float x) {
    return 1.0f / (1.0f + __expf(-x));
}
__device__ __forceinline__ float tanh_fast(float x) {
    float cx = fminf(fmaxf(x, -15.0f), 15.0f);
    float e = __expf(2.0f * cx);
    return (e - 1.0f) / (e + 1.0f);
}

// ---------- setup: swizzle [Wi|Wh] into MFMA B-fragment order, hi/lo split ----------
// layout: idx = ((c*36 + ki)*3 + t)*64 + lane ; element j -> W[t*1024 + c*16 + (lane&15)][ki*32 + (lane>>4)*8 + j]
__global__ void setup_swizzle(const float* __restrict__ Wi, const float* __restrict__ Wh,
                              short* __restrict__ whi, short* __restrict__ wlo) {
    const int idx = blockIdx.x * 256 + threadIdx.x;
    if (idx >= FRAG_TOTAL) return;
    const int l    = idx & 63;
    const int rest = idx >> 6;
    const int t    = rest % 3;
    const int ki   = (rest / 3) % 36;
    const int c    = rest / 108;
    const int nrow = t * 1024 + c * 16 + (l & 15);
    const int kb   = ki * 32 + (l >> 4) * 8;
    short8 vh, vl;
#pragma unroll
    for (int j = 0; j < 8; ++j) {
        const int k = kb + j;
        float w = (k < 128) ? Wi[(size_t)nrow * 128 + k]
                            : Wh[(size_t)nrow * 1024 + (k - 128)];
        short h, lo2;
        f2pair(w, h, lo2);
        vh[j] = h; vl[j] = lo2;
    }
    *(short8*)(whi + (size_t)idx * 8) = vh;
    *(short8*)(wlo + (size_t)idx * 8) = vl;
}

// ---------- main persistent cooperative kernel ----------
__global__ __launch_bounds__(256, 1) void gru_main(
    const float* __restrict__ feats, const float* __restrict__ labels,
    const float* __restrict__ bi,    const float* __restrict__ bh,
    const float* __restrict__ Wd,    const float* __restrict__ bd,
    const short* __restrict__ whi_sw, const short* __restrict__ wlo_sw,
    short* __restrict__ h_hi, short* __restrict__ h_lo,
    float* __restrict__ ps_f32, float* __restrict__ out)
{
    __shared__ short s_whi[SLAB_ELEMS];   // 108 KB: resident W_hi slab (fragment order)
    __shared__ float s_pred[256];         // ps-phase reduction scratch

    cg::grid_group grid = cg::this_grid();

    const int tid  = threadIdx.x;
    const int lane = tid & 63;
    const int wv   = tid >> 6;            // wave 0..3
    const int q    = lane >> 4;
    const int n16  = lane & 15;
    const int c    = blockIdx.x & 63;     // out-group: h-cols [16c, 16c+16)
    const int r    = blockIdx.x >> 6;     // batch-group: rows [128r, 128r+128)

    // stage W_hi slab: contiguous 110592 B
    {
        const f32x4* src = (const f32x4*)(whi_sw + (size_t)c * SLAB_ELEMS);
        f32x4* dst = (f32x4*)s_whi;
        for (int i = tid; i < SLAB_ELEMS / 8; i += 256) dst[i] = src[i];
    }
    __syncthreads();

    const int mbase = r * 128 + wv * 32;  // this wave's batch rows (2 mtiles of 16)
    const int row_r = c * 16 + n16;       // gate row (within r-part) == D col for all tiles
    const float bias_r  = bi[row_r] + bh[row_r];
    const float bias_z  = bi[1024 + row_r] + bh[1024 + row_r];
    const float bias_ni = bi[2048 + row_r];
    const float bias_nh = bh[2048 + row_r];
    const int hcol = row_r;
    const short* wlo_c = wlo_sw + (size_t)c * SLAB_ELEMS;

    for (int step = 0; step < NSTEPS; ++step) {
        const int  cur = step & 1, nxt = cur ^ 1;
        const bool dec = (step >= SENC);
        const int  t   = dec ? step - SENC : step;

        floatx4 aR[2], aZ[2], aNi[2], aNh[2];
#pragma unroll
        for (int mt = 0; mt < 2; ++mt) {
            aR[mt]  = (floatx4){bias_r,  bias_r,  bias_r,  bias_r};
            aZ[mt]  = (floatx4){bias_z,  bias_z,  bias_z,  bias_z};
            aNi[mt] = (floatx4){bias_ni, bias_ni, bias_ni, bias_ni};
            aNh[mt] = (floatx4){bias_nh, bias_nh, bias_nh, bias_nh};
        }

        // ---- region 1: x part (k 0..127), fp32 sources -> hi/lo in-register ----
#pragma unroll
        for (int ki = 0; ki < 4; ++ki) {
            const int fo = ((ki * 3) * 64 + lane) * 8;
            short8 b0 = *(const short8*)(s_whi + fo);
            short8 b1 = *(const short8*)(s_whi + fo + 512);
            short8 b2 = *(const short8*)(s_whi + fo + 1024);
            short8 l0 = *(const short8*)(wlo_c + fo);
            short8 l1 = *(const short8*)(wlo_c + fo + 512);
            short8 l2 = *(const short8*)(wlo_c + fo + 1024);
#pragma unroll
            for (int mt = 0; mt < 2; ++mt) {
                const int b = mbase + mt * 16 + n16;
                const float* src;
                if (ki < 2)      src = feats  + ((size_t)b * 159 + step) * 64 + ki * 32 + q * 8;
                else if (!dec)   src = labels + ((size_t)b * 128 + t) * 64 + (ki - 2) * 32 + q * 8;
                else             src = ps_f32 + (size_t)b * 64 + (ki - 2) * 32 + q * 8;
                short8 ah, al;
                cvt8(src, ah, al);
                aR[mt]  = MFMA(ah, b0, aR[mt]);  aR[mt]  = MFMA(ah, l0, aR[mt]);  aR[mt]  = MFMA(al, b0, aR[mt]);
                aZ[mt]  = MFMA(ah, b1, aZ[mt]);  aZ[mt]  = MFMA(ah, l1, aZ[mt]);  aZ[mt]  = MFMA(al, b1, aZ[mt]);
                aNi[mt] = MFMA(ah, b2, aNi[mt]); aNi[mt] = MFMA(ah, l2, aNi[mt]); aNi[mt] = MFMA(al, b2, aNi[mt]);
            }
        }

        // ---- region 2: h part (k 128..1151), bf16 hi/lo buffers ----
        {
            const short* hbh = h_hi + (size_t)cur * HB;
            const short* hbl = h_lo + (size_t)cur * HB;
#pragma unroll 4
            for (int ki = 4; ki < 36; ++ki) {
                const int fo = ((ki * 3) * 64 + lane) * 8;
                short8 b0 = *(const short8*)(s_whi + fo);
                short8 b1 = *(const short8*)(s_whi + fo + 512);
                short8 b2 = *(const short8*)(s_whi + fo + 1024);
                short8 l0 = *(const short8*)(wlo_c + fo);
                short8 l1 = *(const short8*)(wlo_c + fo + 512);
                short8 l2 = *(const short8*)(wlo_c + fo + 1024);
                const int hk = (ki - 4) * 32 + q * 8;
#pragma unroll
                for (int mt = 0; mt < 2; ++mt) {
                    const int b = mbase + mt * 16 + n16;
                    short8 ah = *(const short8*)(hbh + (size_t)b * 1024 + hk);
                    short8 al = *(const short8*)(hbl + (size_t)b * 1024 + hk);
                    aR[mt]  = MFMA(ah, b0, aR[mt]);  aR[mt]  = MFMA(ah, l0, aR[mt]);  aR[mt]  = MFMA(al, b0, aR[mt]);
                    aZ[mt]  = MFMA(ah, b1, aZ[mt]);  aZ[mt]  = MFMA(ah, l1, aZ[mt]);  aZ[mt]  = MFMA(al, b1, aZ[mt]);
                    aNh[mt] = MFMA(ah, b2, aNh[mt]); aNh[mt] = MFMA(ah, l2, aNh[mt]); aNh[mt] = MFMA(al, b2, aNh[mt]);
                }
            }
        }

        // ---- epilogue: GRU update, write h (hi/lo) to the other buffer ----
        {
            const short* hbh = h_hi + (size_t)cur * HB;
            const short* hbl = h_lo + (size_t)cur * HB;
            short* nhh = h_hi + (size_t)nxt * HB;
            short* nhl = h_lo + (size_t)nxt * HB;
#pragma unroll
            for (int mt = 0; mt < 2; ++mt) {
#pragma unroll
                for (int i = 0; i < 4; ++i) {
                    const int b = mbase + mt * 16 + q * 4 + i;   // D row = (lane>>4)*4 + reg
                    float rr = sigm(aR[mt][i]);
                    float zz = sigm(aZ[mt][i]);
                    float nn = tanh_fast(aNi[mt][i] + rr * aNh[mt][i]);
                    const size_t idx = (size_t)b * 1024 + hcol;
                    float hold = bf2f(hbh[idx]) + bf2f(hbl[idx]);
                    float hv = (1.0f - zz) * nn + zz * hold;
                    short sh, sl;
                    f2pair(hv, sh, sl);
                    nhh[idx] = sh;
                    nhl[idx] = sl;
                }
            }
        }
        grid.sync();

        // ---- ps phase: after encoder (step 127) and every decoder step ----
        if (step >= SENC - 1) {
            const int ot  = step - (SENC - 1);       // output time index 0..31
            const int hb2 = (step + 1) & 1;          // buffer holding the just-written h
            const short* hh = h_hi + (size_t)hb2 * HB;
            const short* hl = h_lo + (size_t)hb2 * HB;
            const int p = tid >> 1, half = tid & 1;
            const int b = 2 * blockIdx.x + (p >> 6);
            const int o = p & 63;
            const float* wrow = Wd + (size_t)o * 1024 + half * 512;
            const short* hrh  = hh + (size_t)b * 1024 + half * 512;
            const short* hrl  = hl + (size_t)b * 1024 + half * 512;
            float acc = 0.0f;
#pragma unroll 4
            for (int k = 0; k < 512; k += 4) {
                const unsigned* ph = (const unsigned*)(hrh + k);
                const unsigned* pl = (const unsigned*)(hrl + k);
                unsigned a0 = ph[0], a1 = ph[1], c0 = pl[0], c1 = pl[1];
                f32x4 w = *(const f32x4*)(wrow + k);
                float h0 = __uint_as_float(a0 << 16)          + __uint_as_float(c0 << 16);
                float h1 = __uint_as_float(a0 & 0xFFFF0000u)  + __uint_as_float(c0 & 0xFFFF0000u);
                float h2 = __uint_as_float(a1 << 16)          + __uint_as_float(c1 << 16);
                float h3 = __uint_as_float(a1 & 0xFFFF0000u)  + __uint_as_float(c1 & 0xFFFF0000u);
                acc += h0 * w[0] + h1 * w[1] + h2 * w[2] + h3 * w[3];
            }
            s_pred[tid] = acc;
            __syncthreads();
            if (tid < 128) {
                const int b2 = 2 * blockIdx.x + (tid >> 6);
                const int o2 = tid & 63;
                float v = s_pred[2 * tid] + s_pred[2 * tid + 1] + bd[o2];
                out[((size_t)ot * 512 + b2) * 64 + o2] = v;
                ps_f32[(size_t)b2 * 64 + o2] = v;
            }
            grid.sync();
        }
    }
}

extern "C" void kernel_launch(void* const* d_in, const int* in_sizes, int n_in,
                              void* d_out, int out_size, void* d_ws, size_t ws_size,
                              hipStream_t stream) {
    const float* feats  = (const float*)d_in[0];
    const float* labels = (const float*)d_in[1];
    const float* Wi     = (const float*)d_in[2];
    const float* Wh     = (const float*)d_in[3];
    const float* bi     = (const float*)d_in[4];
    const float* bh     = (const float*)d_in[5];
    const float* Wd     = (const float*)d_in[6];
    const float* bd     = (const float*)d_in[7];
    float* out = (float*)d_out;

    char* ws = (char*)d_ws;
    short* whi_sw = (short*)(ws);                       // 7,077,888 B
    short* wlo_sw = (short*)(ws + 7077888);             // 7,077,888 B
    short* h_hi   = (short*)(ws + 14155776);            // 2,097,152 B (2 buffers)
    short* h_lo   = (short*)(ws + 16252928);            // 2,097,152 B
    float* ps_f32 = (float*)(ws + 18350080);            //   131,072 B

    // zero h buffer 0 (buffer 1 is written before first read)
    hipMemsetAsync(h_hi, 0, 1048576, stream);
    hipMemsetAsync(h_lo, 0, 1048576, stream);

    setup_swizzle<<<FRAG_TOTAL / 256, 256, 0, stream>>>(Wi, Wh, whi_sw, wlo_sw);

    void* args[] = {(void*)&feats, (void*)&labels, (void*)&bi, (void*)&bh,
                    (void*)&Wd, (void*)&bd, (void*)&whi_sw, (void*)&wlo_sw,
                    (void*)&h_hi, (void*)&h_lo, (void*)&ps_f32, (void*)&out};
    hipLaunchCooperativeKernel(reinterpret_cast<void*>(gru_main),
                               dim3(256), dim3(256), args, 0, stream);
}